// Round 4
// baseline (161.756 us; speedup 1.0000x reference)
//
#include <hip/hip_runtime.h>

// ---------------- problem constants (fixed by reference) ----------------
#define T_DIM 110
#define B_DIM 256
#define D_DIM 512
#define H_DIM 512
#define K_CAT 1024              // concat K: [fr(512) | fi(512)]
#define M_DIM (T_DIM * B_DIM)   // 28160
#define BD    (B_DIM * D_DIM)   // 131072
#define EPSV 1e-9f

typedef float f32x4 __attribute__((ext_vector_type(4)));
typedef short bf16x8 __attribute__((ext_vector_type(8)));

static __device__ __forceinline__ unsigned short f2bf(float f) {
    unsigned u = __builtin_bit_cast(unsigned, f);
    u += 0x7fffu + ((u >> 16) & 1u);      // round-to-nearest-even
    return (unsigned short)(u >> 16);
}

// ---------------- kernel 1: weight prep  Wp=W1+W2 | Wm=W1-W2 (bf16), bias=2*b1 ----
__global__ __launch_bounds__(256) void prep_w_kernel(
    const float* __restrict__ W1, const float* __restrict__ b1,
    const float* __restrict__ W2,
    unsigned short* __restrict__ Bt,   // [H][K_CAT] bf16  (B^T layout: [N][K])
    float* __restrict__ bias2)         // [H]
{
    int i = blockIdx.x * 256 + threadIdx.x;
    if (i < H_DIM) bias2[i] = 2.0f * b1[i];
    if (i >= H_DIM * K_CAT) return;
    int h = i / K_CAT;
    int k = i % K_CAT;
    float w;
    if (k < D_DIM) w = W1[h * D_DIM + k] + W2[h * D_DIM + k];
    else           w = W1[h * D_DIM + k - D_DIM] - W2[h * D_DIM + k - D_DIM];
    Bt[i] = f2bf(w);
}

// ---------------- kernel 2: fused features + scan -> A[M][K_CAT] bf16 ----------
// One thread per (b,d). Serial over t. Latency hiding via global_load_lds into a
// wave-private LDS ring (depth 8, prefetch distance 4) with counted vmcnt that
// NEVER drains (T4 idiom). No barriers in the loop: each wave stages and reads
// only its own 64-lane slice. Event math per wave per iter: 5 stages + 2 stores;
// steady-state events younger than the oldest needed stage = 28; wait vmcnt(24)
// (4-event safety margin). Empty asm memory-clobbers pin window ordering.
#define RING 8
#define PFD  4            // prefetch distance (iterations)

__global__ __launch_bounds__(256) void feat_scan_kernel(
    const float* __restrict__ a, const float* __restrict__ v,
    const float* __restrict__ l, const float* __restrict__ qmask,
    const float* __restrict__ mu_a, const float* __restrict__ mu_v,
    const float* __restrict__ mu_l,
    const float* __restrict__ shifta, const float* __restrict__ shiftv,
    const float* __restrict__ turna, const float* __restrict__ turnb,
    unsigned short* __restrict__ A)    // [M][K_CAT] bf16
{
    // ring slot: a[256] v[256] l[256] ta[256] tb[256] floats (1280 f / 5 KB)
    __shared__ float ring[RING * 1280];
    __shared__ float qm_s[T_DIM];
    __shared__ float mu_s[3 * T_DIM];

    const int tx = threadIdx.x;
    const int b = blockIdx.x >> 1;            // block's fixed batch index
    const int dbase = (blockIdx.x & 1) << 8;  // 0 or 256
    const int d = dbase + tx;
    const size_t gAVL = (size_t)b * D_DIM + d;   // offset within one t-plane

    if (tx < T_DIM) {
        qm_s[tx] = qmask[(size_t)(tx * B_DIM + b) * 2];
        mu_s[tx]             = mu_a[tx];
        mu_s[T_DIM + tx]     = mu_v[tx];
        mu_s[2 * T_DIM + tx] = mu_l[tx];
    }
    const float sa = shifta[d & 511];
    const float sv = shiftv[d & 511];
    __syncthreads();   // once, before any staging

#define GLL(gp, lp) __builtin_amdgcn_global_load_lds(                          \
        (const __attribute__((address_space(1))) unsigned int*)(gp),           \
        (__attribute__((address_space(3))) unsigned int*)(lp), 4, 0, 0)

#define STAGE(tt, sl)                                                          \
    {                                                                          \
        const int t_ = (tt); const int s_ = (sl);                              \
        GLL(a + (size_t)t_ * BD + gAVL,   &ring[s_ * 1280 +        tx]);       \
        GLL(v + (size_t)t_ * BD + gAVL,   &ring[s_ * 1280 +  256 + tx]);       \
        GLL(l + (size_t)t_ * BD + gAVL,   &ring[s_ * 1280 +  512 + tx]);       \
        GLL(turna + t_ * D_DIM + d,       &ring[s_ * 1280 +  768 + tx]);       \
        GLL(turnb + t_ * D_DIM + d,       &ring[s_ * 1280 + 1024 + tx]);       \
    }
#define SEP asm volatile("" ::: "memory")

    // ---- prologue: stage slots 0..3, then 8 dummy re-stage events so that
    // iteration 0's vmcnt sees the steady-state count. SEPs pin the order.
    STAGE(0, 0); SEP;
    STAGE(1, 1); SEP;
    STAGE(2, 2); SEP;
    STAGE(3, 3); SEP;
    // 8 dummy events (idempotent re-stage of slot 3 with identical data)
    STAGE(3, 3); SEP;
    GLL(a + (size_t)3 * BD + gAVL, &ring[3 * 1280 +       tx]);
    GLL(v + (size_t)3 * BD + gAVL, &ring[3 * 1280 + 256 + tx]);
    GLL(l + (size_t)3 * BD + gAVL, &ring[3 * 1280 + 512 + tx]);
    SEP;

    float pAr = 0.f, pAi = 0.f, pBr = 0.f, pBi = 0.f;

    for (int t = 0; t < T_DIM; ++t) {
        // stage t+PFD (clamped source; dest slot keeps the unclamped index so
        // the per-iter event count stays constant)
        const int tn = t + PFD;
        STAGE(tn <= T_DIM - 1 ? tn : T_DIM - 1, tn & (RING - 1));
        // counted wait: oldest stage group (for step t) has >=28 younger
        // events in steady state; 24 leaves a 4-event safety margin.
        asm volatile("s_waitcnt vmcnt(24)" ::: "memory");

        const int sl = t & (RING - 1);
        const float av  = ring[sl * 1280 +        tx];
        const float vv  = ring[sl * 1280 +  256 + tx];
        const float lv  = ring[sl * 1280 +  512 + tx];
        const float tav = ring[sl * 1280 +  768 + tx];
        const float tbv = ring[sl * 1280 + 1024 + tx];
        const float qa  = qm_s[t];
        const float ma  = mu_s[t];
        const float mv  = mu_s[T_DIM + t];
        const float ml  = mu_s[2 * T_DIM + t];

        float sA, cA, sV, cV, sL, cL;
        __sincosf(av + sa, &sA, &cA);
        __sincosf(vv + sv, &sV, &cV);
        __sincosf(lv,      &sL, &cL);
        float fr = ml * cL + ma * cA + mv * cV;
        float fi = ml * sL + ma * sA + mv * sV;

        const bool isA = qa > 0.5f;
        if (t == 0) {
            pAr = isA ? fr : 1.0f;  pAi = isA ? fi : 1.0f;
            pBr = isA ? 1.0f : fr;  pBi = isA ? 1.0f : fi;
        } else {
            const float ph = isA ? tav : tbv;
            const float pr = isA ? pAr : pBr;
            const float pi = isA ? pAi : pBi;
            float sp, cp;
            __sincosf(ph, &sp, &cp);
            float tr = pr * cp - pi * sp;
            float ti = pr * sp + pi * cp;
            if (!(tr == 0.0f && ti == 0.0f)) {
                const float inv = 1.0f / (sqrtf(tr * tr + ti * ti) + EPSV);
                tr *= inv; ti *= inv;
            }
            fr += tr;
            fi += ti;
            if (isA) { pAr = fr; pAi = fi; } else { pBr = fr; pBi = fi; }
        }

        const size_t row = (size_t)(t * B_DIM + b) * K_CAT;
        A[row + d]         = f2bf(fr);
        A[row + D_DIM + d] = f2bf(fi);
    }
#undef GLL
#undef STAGE
#undef SEP
}

// ---------------- kernel 3: bf16 MFMA GEMM  C = A @ Bt^T + bias ---------------
// m97 structure: 128x128 tile, BK=64, global_load_lds width-16 staging into
// LINEAR LDS [128][64], 4 waves (2x2), each wave 64x64 via 4x4 frags of
// 16x16x32, 2 barriers per K-step.
#define BM 128
#define BN 128
#define BK 64

__global__ __launch_bounds__(256) void gemm_kernel(
    const unsigned short* __restrict__ A,
    const unsigned short* __restrict__ Bt,
    const float* __restrict__ bias2,
    float* __restrict__ C)
{
    __shared__ __align__(16) unsigned short As[BM * BK];   // 16 KB, linear
    __shared__ __align__(16) unsigned short Bs[BN * BK];   // 16 KB, linear

    const int tid = threadIdx.x;
    const int wave = tid >> 6;
    const int lane = tid & 63;
    const int wr = wave >> 1;          // 0..1 (M dir)
    const int wc = wave & 1;           // 0..1 (N dir)
    const int m0 = blockIdx.x * BM;
    const int n0 = blockIdx.y * BN;
    const int lrow = lane & 15;
    const int lk8 = (lane >> 4) * 8;   // k-offset of this lane's 8 elements

    const int srow = wave * 32;        // first row this wave stages
    const int lrow8 = lane >> 3;       // row within 8-row group
    const int lchunk = lane & 7;       // 16B chunk within row

    f32x4 acc[4][4] = {};

    for (int k0 = 0; k0 < K_CAT; k0 += BK) {
        #pragma unroll
        for (int c = 0; c < 4; ++c) {
            const int row = srow + c * 8 + lrow8;
            {
                const unsigned short* gp = A + (size_t)(m0 + row) * K_CAT + k0 + lchunk * 8;
                unsigned short* lp = As + (srow + c * 8) * BK + lane * 8;
                __builtin_amdgcn_global_load_lds(
                    (const __attribute__((address_space(1))) unsigned int*)gp,
                    (__attribute__((address_space(3))) unsigned int*)lp,
                    16, 0, 0);
            }
            {
                const unsigned short* gp = Bt + (size_t)(n0 + row) * K_CAT + k0 + lchunk * 8;
                unsigned short* lp = Bs + (srow + c * 8) * BK + lane * 8;
                __builtin_amdgcn_global_load_lds(
                    (const __attribute__((address_space(1))) unsigned int*)gp,
                    (__attribute__((address_space(3))) unsigned int*)lp,
                    16, 0, 0);
            }
        }
        __syncthreads();

        bf16x8 af[4][2], bfv[4][2];
        #pragma unroll
        for (int m = 0; m < 4; ++m)
            #pragma unroll
            for (int kk = 0; kk < 2; ++kk)
                af[m][kk] = *reinterpret_cast<const bf16x8*>(
                    &As[(wr * 64 + m * 16 + lrow) * BK + kk * 32 + lk8]);
        #pragma unroll
        for (int n = 0; n < 4; ++n)
            #pragma unroll
            for (int kk = 0; kk < 2; ++kk)
                bfv[n][kk] = *reinterpret_cast<const bf16x8*>(
                    &Bs[(wc * 64 + n * 16 + lrow) * BK + kk * 32 + lk8]);

        #pragma unroll
        for (int kk = 0; kk < 2; ++kk)
            #pragma unroll
            for (int m = 0; m < 4; ++m)
                #pragma unroll
                for (int n = 0; n < 4; ++n)
                    acc[m][n] = __builtin_amdgcn_mfma_f32_16x16x32_bf16(
                        af[m][kk], bfv[n][kk], acc[m][n], 0, 0, 0);
        __syncthreads();
    }

    // -------- epilogue: C/D layout col=lane&15, row=(lane>>4)*4+r  (m89/m91)
    const int rbase = m0 + wr * 64 + (lane >> 4) * 4;
    const int cbase = n0 + wc * 64;
    #pragma unroll
    for (int n = 0; n < 4; ++n) {
        const int col = cbase + n * 16 + lrow;
        const float bv = bias2[col];
        #pragma unroll
        for (int m = 0; m < 4; ++m) {
            const int row0 = rbase + m * 16;
            #pragma unroll
            for (int r = 0; r < 4; ++r) {
                C[(size_t)(row0 + r) * H_DIM + col] = acc[m][n][r] + bv;
            }
        }
    }
}

// ---------------- launcher ----------------
extern "C" void kernel_launch(void* const* d_in, const int* in_sizes, int n_in,
                              void* d_out, int out_size, void* d_ws, size_t ws_size,
                              hipStream_t stream) {
    const float* a      = (const float*)d_in[0];
    const float* v      = (const float*)d_in[1];
    const float* l      = (const float*)d_in[2];
    const float* qmask  = (const float*)d_in[3];
    // d_in[4] umask: unused by reference
    const float* mu_a   = (const float*)d_in[5];
    const float* mu_v   = (const float*)d_in[6];
    const float* mu_l   = (const float*)d_in[7];
    const float* shifta = (const float*)d_in[8];
    const float* shiftv = (const float*)d_in[9];
    const float* turna  = (const float*)d_in[10];
    const float* turnb  = (const float*)d_in[11];
    const float* W1     = (const float*)d_in[12];
    const float* b1     = (const float*)d_in[13];
    const float* W2     = (const float*)d_in[14];
    // d_in[15] b2: cancels in xr+xi
    float* out = (float*)d_out;

    char* ws = (char*)d_ws;
    unsigned short* Afeat = (unsigned short*)ws;                       // M*K_CAT bf16
    size_t offB  = (size_t)M_DIM * K_CAT * sizeof(unsigned short);
    unsigned short* Bt = (unsigned short*)(ws + offB);                 // H*K_CAT bf16
    size_t offBias = offB + (size_t)H_DIM * K_CAT * sizeof(unsigned short);
    float* bias2 = (float*)(ws + offBias);

    prep_w_kernel<<<(H_DIM * K_CAT + 255) / 256, 256, 0, stream>>>(W1, b1, W2, Bt, bias2);
    feat_scan_kernel<<<(B_DIM * D_DIM) / 256, 256, 0, stream>>>(
        a, v, l, qmask, mu_a, mu_v, mu_l, shifta, shiftv, turna, turnb, Afeat);
    dim3 grid(M_DIM / BM, H_DIM / BN);
    gemm_kernel<<<grid, 256, 0, stream>>>(Afeat, Bt, bias2, out);
}

// Round 6
// 113.460 us; speedup vs baseline: 1.4257x; 1.4257x over previous
//
#include <hip/hip_runtime.h>

// ---------------- problem constants (fixed by reference) ----------------
#define T_DIM 110
#define B_DIM 256
#define D_DIM 512
#define H_DIM 512
#define K_CAT 1024              // K layout: interleaved (fr0,fi0,fr1,fi1,...)
#define M_DIM (T_DIM * B_DIM)   // 28160
#define BD    (B_DIM * D_DIM)   // 131072
#define EPSV 1e-9f

typedef float f32x4 __attribute__((ext_vector_type(4)));
typedef short bf16x8 __attribute__((ext_vector_type(8)));

static __device__ __forceinline__ unsigned short f2bf(float f) {
    unsigned u = __builtin_bit_cast(unsigned, f);
    u += 0x7fffu + ((u >> 16) & 1u);      // round-to-nearest-even
    return (unsigned short)(u >> 16);
}

// ---------------- kernel 1: weight prep, INTERLEAVED columns ------------------
// Bt[h][2j] = (W1+W2)[h][j]  (multiplies fr_j);  Bt[h][2j+1] = (W1-W2)[h][j]
// (multiplies fi_j). bias = 2*b1 (b2 cancels in xr+xi).
__global__ __launch_bounds__(256) void prep_w_kernel(
    const float* __restrict__ W1, const float* __restrict__ b1,
    const float* __restrict__ W2,
    unsigned short* __restrict__ Bt,   // [H][K_CAT] bf16
    float* __restrict__ bias2)         // [H]
{
    int i = blockIdx.x * 256 + threadIdx.x;
    if (i < H_DIM) bias2[i] = 2.0f * b1[i];
    if (i >= H_DIM * K_CAT) return;
    int h = i / K_CAT;
    int k = i % K_CAT;
    int j = k >> 1;
    float w = (k & 1) ? (W1[h * D_DIM + j] - W2[h * D_DIM + j])
                      : (W1[h * D_DIM + j] + W2[h * D_DIM + j]);
    Bt[i] = f2bf(w);
}

// ---------------- kernel 1b: turn-phase sincos table TT[t][d] = (ca,sa,cb,sb) --
__global__ __launch_bounds__(256) void prep_tt_kernel(
    const float* __restrict__ turna, const float* __restrict__ turnb,
    float4* __restrict__ TT)
{
    int i = blockIdx.x * 256 + threadIdx.x;
    if (i >= T_DIM * D_DIM) return;
    float s1, c1, s2, c2;
    __sincosf(turna[i], &s1, &c1);
    __sincosf(turnb[i], &s2, &c2);
    TT[i] = make_float4(c1, s1, c2, s2);
}

// ---------------- kernel 2: fused features + scan -> A[M][K_CAT] bf16 ----------
// Thread = one (b,d). f stays f32 through the recurrence (bf16 f before the
// normalize step amplifies error 1/|p| — R5 lesson). Depth-3 register prefetch
// ring, pinned by sched_barrier(0); branchless single-BB body; packed bf16x2
// store per iter.
__global__ __launch_bounds__(256) void feat_scan_kernel(
    const float* __restrict__ a, const float* __restrict__ v,
    const float* __restrict__ l, const float* __restrict__ qmask,
    const float* __restrict__ mu_a, const float* __restrict__ mu_v,
    const float* __restrict__ mu_l,
    const float* __restrict__ shifta, const float* __restrict__ shiftv,
    const float4* __restrict__ TT,
    unsigned int* __restrict__ A32)    // [M][K_CAT/2] dwords (fr|fi<<16)
{
    __shared__ float qm_s[T_DIM], mua_s[T_DIM], muv_s[T_DIM], mul_s[T_DIM];
    const int tx = threadIdx.x;
    const int b  = blockIdx.x >> 1;
    const int d  = ((blockIdx.x & 1) << 8) + tx;
    if (tx < T_DIM) {
        qm_s[tx]  = qmask[(size_t)(tx * B_DIM + b) * 2];
        mua_s[tx] = mu_a[tx];
        muv_s[tx] = mu_v[tx];
        mul_s[tx] = mu_l[tx];
    }
    const float sa = shifta[d];
    const float sv = shiftv[d];
    __syncthreads();

    const size_t gbase = (size_t)b * D_DIM + d;

#define LDSET(A_,V_,L_,T4_,Q_,MA_,MV_,ML_, tt_)                                \
    { const int t_ = (tt_);                                                    \
      A_  = a[(size_t)t_ * BD + gbase];                                        \
      V_  = v[(size_t)t_ * BD + gbase];                                        \
      L_  = l[(size_t)t_ * BD + gbase];                                        \
      T4_ = TT[t_ * D_DIM + d];                                                \
      Q_  = qm_s[t_]; MA_ = mua_s[t_]; MV_ = muv_s[t_]; ML_ = mul_s[t_]; }

    float a0,v0,l0,q0,ma0,mv0,ml0; float4 tt0;
    float a1,v1,l1,q1,ma1,mv1,ml1; float4 tt1;
    float a2,v2,l2,q2,ma2,mv2,ml2; float4 tt2;
    LDSET(a0,v0,l0,tt0,q0,ma0,mv0,ml0, 0)
    LDSET(a1,v1,l1,tt1,q1,ma1,mv1,ml1, 1)
    LDSET(a2,v2,l2,tt2,q2,ma2,mv2,ml2, 2)

    // pre-init (1,1): combined with gate=0 at t=0, the generic select below
    // reproduces the reference's t=0 rule exactly.
    float pAr = 1.f, pAi = 1.f, pBr = 1.f, pBi = 1.f;

    #pragma unroll 3
    for (int t = 0; t < T_DIM; ++t) {
        // issue loads for t+3 (3 iterations of latency budget), then fence.
        float aN,vN,lN,qN,maN,mvN,mlN; float4 ttN;
        const int tp = (t + 3 < T_DIM) ? t + 3 : T_DIM - 1;
        LDSET(aN,vN,lN,ttN,qN,maN,mvN,mlN, tp)
        __builtin_amdgcn_sched_barrier(0);

        float sA,cA,sV,cV,sL,cL;
        __sincosf(a0 + sa, &sA, &cA);
        __sincosf(v0 + sv, &sV, &cV);
        __sincosf(l0,      &sL, &cL);
        float fr = ml0 * cL + ma0 * cA + mv0 * cV;
        float fi = ml0 * sL + ma0 * sA + mv0 * sV;

        const bool isA = q0 > 0.5f;
        const float cp = isA ? tt0.x : tt0.z;
        const float sp = isA ? tt0.y : tt0.w;
        const float pr = isA ? pAr : pBr;
        const float pi = isA ? pAi : pBi;
        float tr = pr * cp - pi * sp;
        float ti = pr * sp + pi * cp;
        // gate: kills the turn term at t=0; 0*(1/eps)=0 also handles turn==0.
        const float gate = (t == 0) ? 0.0f : 1.0f;
        const float inv = gate / (sqrtf(tr * tr + ti * ti) + EPSV);
        fr += tr * inv;
        fi += ti * inv;
        pAr = isA ? fr : pAr;  pAi = isA ? fi : pAi;
        pBr = isA ? pBr : fr;  pBi = isA ? pBi : fi;

        A32[(size_t)(t * B_DIM + b) * (K_CAT / 2) + d] =
            (unsigned)f2bf(fr) | ((unsigned)f2bf(fi) << 16);

        // rotate ring (renamed away under unroll-3)
        a0=a1; v0=v1; l0=l1; tt0=tt1; q0=q1; ma0=ma1; mv0=mv1; ml0=ml1;
        a1=a2; v1=v2; l1=l2; tt1=tt2; q1=q2; ma1=ma2; mv1=mv2; ml1=ml2;
        a2=aN; v2=vN; l2=lN; tt2=ttN; q2=qN; ma2=maN; mv2=mvN; ml2=mlN;
    }
#undef LDSET
}

// ---------------- kernel 3: bf16 MFMA GEMM  C = A @ Bt^T + bias ---------------
// m97 structure: 128x128 tile, BK=64, global_load_lds width-16 staging into
// LINEAR LDS [128][64], 4 waves (2x2), each wave 64x64 via 4x4 frags of
// 16x16x32, 2 barriers per K-step.
#define BM 128
#define BN 128
#define BK 64

__global__ __launch_bounds__(256) void gemm_kernel(
    const unsigned short* __restrict__ A,
    const unsigned short* __restrict__ Bt,
    const float* __restrict__ bias2,
    float* __restrict__ C)
{
    __shared__ __align__(16) unsigned short As[BM * BK];   // 16 KB, linear
    __shared__ __align__(16) unsigned short Bs[BN * BK];   // 16 KB, linear

    const int tid = threadIdx.x;
    const int wave = tid >> 6;
    const int lane = tid & 63;
    const int wr = wave >> 1;          // 0..1 (M dir)
    const int wc = wave & 1;           // 0..1 (N dir)
    const int m0 = blockIdx.x * BM;
    const int n0 = blockIdx.y * BN;
    const int lrow = lane & 15;
    const int lk8 = (lane >> 4) * 8;   // k-offset of this lane's 8 elements

    const int srow = wave * 32;        // first row this wave stages
    const int lrow8 = lane >> 3;       // row within 8-row group
    const int lchunk = lane & 7;       // 16B chunk within row

    f32x4 acc[4][4] = {};

    for (int k0 = 0; k0 < K_CAT; k0 += BK) {
        #pragma unroll
        for (int c = 0; c < 4; ++c) {
            const int row = srow + c * 8 + lrow8;
            {
                const unsigned short* gp = A + (size_t)(m0 + row) * K_CAT + k0 + lchunk * 8;
                unsigned short* lp = As + (srow + c * 8) * BK + lane * 8;
                __builtin_amdgcn_global_load_lds(
                    (const __attribute__((address_space(1))) unsigned int*)gp,
                    (__attribute__((address_space(3))) unsigned int*)lp,
                    16, 0, 0);
            }
            {
                const unsigned short* gp = Bt + (size_t)(n0 + row) * K_CAT + k0 + lchunk * 8;
                unsigned short* lp = Bs + (srow + c * 8) * BK + lane * 8;
                __builtin_amdgcn_global_load_lds(
                    (const __attribute__((address_space(1))) unsigned int*)gp,
                    (__attribute__((address_space(3))) unsigned int*)lp,
                    16, 0, 0);
            }
        }
        __syncthreads();

        bf16x8 af[4][2], bfv[4][2];
        #pragma unroll
        for (int m = 0; m < 4; ++m)
            #pragma unroll
            for (int kk = 0; kk < 2; ++kk)
                af[m][kk] = *reinterpret_cast<const bf16x8*>(
                    &As[(wr * 64 + m * 16 + lrow) * BK + kk * 32 + lk8]);
        #pragma unroll
        for (int n = 0; n < 4; ++n)
            #pragma unroll
            for (int kk = 0; kk < 2; ++kk)
                bfv[n][kk] = *reinterpret_cast<const bf16x8*>(
                    &Bs[(wc * 64 + n * 16 + lrow) * BK + kk * 32 + lk8]);

        #pragma unroll
        for (int kk = 0; kk < 2; ++kk)
            #pragma unroll
            for (int m = 0; m < 4; ++m)
                #pragma unroll
                for (int n = 0; n < 4; ++n)
                    acc[m][n] = __builtin_amdgcn_mfma_f32_16x16x32_bf16(
                        af[m][kk], bfv[n][kk], acc[m][n], 0, 0, 0);
        __syncthreads();
    }

    // -------- epilogue: C/D layout col=lane&15, row=(lane>>4)*4+r  (m89/m91)
    const int rbase = m0 + wr * 64 + (lane >> 4) * 4;
    const int cbase = n0 + wc * 64;
    #pragma unroll
    for (int n = 0; n < 4; ++n) {
        const int col = cbase + n * 16 + lrow;
        const float bv = bias2[col];
        #pragma unroll
        for (int m = 0; m < 4; ++m) {
            const int row0 = rbase + m * 16;
            #pragma unroll
            for (int r = 0; r < 4; ++r) {
                C[(size_t)(row0 + r) * H_DIM + col] = acc[m][n][r] + bv;
            }
        }
    }
}

// ---------------- launcher ----------------
extern "C" void kernel_launch(void* const* d_in, const int* in_sizes, int n_in,
                              void* d_out, int out_size, void* d_ws, size_t ws_size,
                              hipStream_t stream) {
    const float* a      = (const float*)d_in[0];
    const float* v      = (const float*)d_in[1];
    const float* l      = (const float*)d_in[2];
    const float* qmask  = (const float*)d_in[3];
    // d_in[4] umask: unused by reference
    const float* mu_a   = (const float*)d_in[5];
    const float* mu_v   = (const float*)d_in[6];
    const float* mu_l   = (const float*)d_in[7];
    const float* shifta = (const float*)d_in[8];
    const float* shiftv = (const float*)d_in[9];
    const float* turna  = (const float*)d_in[10];
    const float* turnb  = (const float*)d_in[11];
    const float* W1     = (const float*)d_in[12];
    const float* b1     = (const float*)d_in[13];
    const float* W2     = (const float*)d_in[14];
    // d_in[15] b2: cancels in xr+xi
    float* out = (float*)d_out;

    char* ws = (char*)d_ws;
    unsigned short* Afeat = (unsigned short*)ws;                       // M*K_CAT bf16
    size_t offB  = (size_t)M_DIM * K_CAT * sizeof(unsigned short);     // 57.7 MB
    unsigned short* Bt = (unsigned short*)(ws + offB);                 // H*K_CAT bf16
    size_t offBias = offB + (size_t)H_DIM * K_CAT * sizeof(unsigned short);
    float* bias2 = (float*)(ws + offBias);
    size_t offTT = offBias + 4096;
    float4* TT = (float4*)(ws + offTT);                                // T*D float4

    prep_w_kernel<<<(H_DIM * K_CAT + 255) / 256, 256, 0, stream>>>(W1, b1, W2, Bt, bias2);
    prep_tt_kernel<<<(T_DIM * D_DIM + 255) / 256, 256, 0, stream>>>(turna, turnb, TT);
    feat_scan_kernel<<<B_DIM * 2, 256, 0, stream>>>(
        a, v, l, qmask, mu_a, mu_v, mu_l, shifta, shiftv, TT, (unsigned int*)Afeat);
    dim3 grid(M_DIM / BM, H_DIM / BN);
    gemm_kernel<<<grid, 256, 0, stream>>>(Afeat, Bt, bias2, out);
}

// Round 9
// 112.783 us; speedup vs baseline: 1.4342x; 1.0060x over previous
//
#include <hip/hip_runtime.h>

// ---------------- problem constants (fixed by reference) ----------------
#define T_DIM 110
#define B_DIM 256
#define D_DIM 512
#define H_DIM 512
#define K_CAT 1024              // K layout: interleaved (fr0,fi0,fr1,fi1,...)
#define M_DIM (T_DIM * B_DIM)   // 28160
#define BD    (B_DIM * D_DIM)   // 131072
#define EPSV 1e-9f

typedef float f32x4 __attribute__((ext_vector_type(4)));
typedef short bf16x8 __attribute__((ext_vector_type(8)));

static __device__ __forceinline__ unsigned short f2bf(float f) {
    unsigned u = __builtin_bit_cast(unsigned, f);
    u += 0x7fffu + ((u >> 16) & 1u);      // round-to-nearest-even
    return (unsigned short)(u >> 16);
}

// ---------------- kernel 1: weight prep, INTERLEAVED columns ------------------
// Bt[h][2j] = (W1+W2)[h][j] (multiplies fr_j); Bt[h][2j+1] = (W1-W2)[h][j]
// (multiplies fi_j). bias = 2*b1 (b2 cancels in xr+xi).
__global__ __launch_bounds__(256) void prep_w_kernel(
    const float* __restrict__ W1, const float* __restrict__ b1,
    const float* __restrict__ W2,
    unsigned short* __restrict__ Bt,   // [H][K_CAT] bf16
    float* __restrict__ bias2)         // [H]
{
    int i = blockIdx.x * 256 + threadIdx.x;
    if (i < H_DIM) bias2[i] = 2.0f * b1[i];
    if (i >= H_DIM * K_CAT) return;
    int h = i / K_CAT;
    int k = i % K_CAT;
    int j = k >> 1;
    float w = (k & 1) ? (W1[h * D_DIM + j] - W2[h * D_DIM + j])
                      : (W1[h * D_DIM + j] + W2[h * D_DIM + j]);
    Bt[i] = f2bf(w);
}

// ---------------- kernel 1b: turn-phase sincos table TT[t][d] = (ca,sa,cb,sb) --
__global__ __launch_bounds__(256) void prep_tt_kernel(
    const float* __restrict__ turna, const float* __restrict__ turnb,
    float4* __restrict__ TT)
{
    int i = blockIdx.x * 256 + threadIdx.x;
    if (i >= T_DIM * D_DIM) return;
    float s1, c1, s2, c2;
    __sincosf(turna[i], &s1, &c1);
    __sincosf(turnb[i], &s2, &c2);
    TT[i] = make_float4(c1, s1, c2, s2);
}

// ---------------- kernel 2: fused features + scan -> A[M][K_CAT] bf16 ----------
// Thread = one (b,d). T14 async-STAGE split, plain HIP (R7/R8 lesson: manual
// vmcnt + asm loads is uncountable at HIP level -> crashes; let the compiler
// insert the counted wait at the ds_write anchor instead):
//   iter t: issue loads(t+4) -> regs | ds_write regs(t+2) (loaded 2 iters ago;
//   compiler's vmcnt here covers only old loads -> queue never drains) |
//   ds_read slot t | compute | store. Each thread uses only its own LDS
//   column -> no barriers in the loop. sched_barrier(0) per iter stops the
//   scheduler sinking issue-loads to their ds_write (R2 failure mode).
#define RING 4

__global__ __launch_bounds__(256) void feat_scan_kernel(
    const float* __restrict__ a, const float* __restrict__ v,
    const float* __restrict__ l, const float* __restrict__ qmask,
    const float* __restrict__ mu_a, const float* __restrict__ mu_v,
    const float* __restrict__ mu_l,
    const float* __restrict__ shifta, const float* __restrict__ shiftv,
    const float4* __restrict__ TT,
    unsigned int* __restrict__ A32)    // [M][K_CAT/2] dwords (fr|fi<<16)
{
    __shared__ float  rA[RING][256], rV[RING][256], rL[RING][256];
    __shared__ float4 rT[RING][256];                 // 28 KB total
    __shared__ float qm_s[T_DIM], mua_s[T_DIM], muv_s[T_DIM], mul_s[T_DIM];

    const int tx = threadIdx.x;
    const int b  = blockIdx.x >> 1;
    const int d  = ((blockIdx.x & 1) << 8) + tx;
    if (tx < T_DIM) {
        qm_s[tx]  = qmask[(size_t)(tx * B_DIM + b) * 2];
        mua_s[tx] = mu_a[tx];
        muv_s[tx] = mu_v[tx];
        mul_s[tx] = mu_l[tx];
    }
    const float sa = shifta[d];
    const float sv = shiftv[d];
    __syncthreads();   // once; loop below has no cross-thread LDS traffic

    const size_t gbase = (size_t)b * D_DIM + d;

    // ---- prologue: slots 0,1 written directly; pending sets for t=2,3 ----
    {
        float xa = a[gbase], xv = v[gbase], xl = l[gbase];
        float4 xt = TT[d];
        rA[0][tx] = xa; rV[0][tx] = xv; rL[0][tx] = xl; rT[0][tx] = xt;
        xa = a[(size_t)1 * BD + gbase]; xv = v[(size_t)1 * BD + gbase];
        xl = l[(size_t)1 * BD + gbase]; xt = TT[1 * D_DIM + d];
        rA[1][tx] = xa; rV[1][tx] = xv; rL[1][tx] = xl; rT[1][tx] = xt;
    }
    float  pa1 = a[(size_t)2 * BD + gbase], pv1 = v[(size_t)2 * BD + gbase],
           pl1 = l[(size_t)2 * BD + gbase];
    float4 pt1 = TT[2 * D_DIM + d];
    float  pa2 = a[(size_t)3 * BD + gbase], pv2 = v[(size_t)3 * BD + gbase],
           pl2 = l[(size_t)3 * BD + gbase];
    float4 pt2 = TT[3 * D_DIM + d];

    // pre-init (1,1): with gate=0 at t=0 the generic select reproduces the
    // reference's t=0 rule exactly.
    float pAr = 1.f, pAi = 1.f, pBr = 1.f, pBi = 1.f;

    #pragma unroll 4
    for (int t = 0; t < T_DIM; ++t) {
        // 1. issue loads for t+4 (clamped; duplicates harmless)
        const int tq = (t + 4 < T_DIM) ? t + 4 : T_DIM - 1;
        const float  qa_ = a[(size_t)tq * BD + gbase];
        const float  qv_ = v[(size_t)tq * BD + gbase];
        const float  ql_ = l[(size_t)tq * BD + gbase];
        const float4 qt_ = TT[tq * D_DIM + d];

        // 2. anchor: write set(t+2), loaded 2 iterations ago. The compiler's
        //    vmcnt before these ds_writes counts only loads >=2 iters old.
        const int ws = (t + 2) & (RING - 1);
        rA[ws][tx] = pa1; rV[ws][tx] = pv1; rL[ws][tx] = pl1; rT[ws][tx] = pt1;

        // 3. read slot t (written at iter t-2; long complete)
        const int rs = t & (RING - 1);
        const float  av = rA[rs][tx];
        const float  vv = rV[rs][tx];
        const float  lv = rL[rs][tx];
        const float4 tt = rT[rs][tx];

        // 4. compute (identical numerics to R6, absmax 0.03125)
        const float qa = qm_s[t], ma = mua_s[t], mv = muv_s[t], ml = mul_s[t];
        float sA, cA, sV, cV, sL, cL;
        __sincosf(av + sa, &sA, &cA);
        __sincosf(vv + sv, &sV, &cV);
        __sincosf(lv,      &sL, &cL);
        float fr = ml * cL + ma * cA + mv * cV;
        float fi = ml * sL + ma * sA + mv * sV;

        const bool isA = qa > 0.5f;
        const float cp = isA ? tt.x : tt.z;
        const float sp = isA ? tt.y : tt.w;
        const float pr = isA ? pAr : pBr;
        const float pi = isA ? pAi : pBi;
        float tr = pr * cp - pi * sp;
        float ti = pr * sp + pi * cp;
        const float gate = (t == 0) ? 0.0f : 1.0f;   // also handles turn==0
        const float inv = gate / (sqrtf(tr * tr + ti * ti) + EPSV);
        fr += tr * inv;
        fi += ti * inv;
        pAr = isA ? fr : pAr;  pAi = isA ? fi : pAi;
        pBr = isA ? pBr : fr;  pBi = isA ? pBi : fi;

        A32[(size_t)(t * B_DIM + b) * (K_CAT / 2) + d] =
            (unsigned)f2bf(fr) | ((unsigned)f2bf(fi) << 16);

        // 5. rotate pending sets (register rename under unroll)
        pa1 = pa2; pv1 = pv2; pl1 = pl2; pt1 = pt2;
        pa2 = qa_; pv2 = qv_; pl2 = ql_; pt2 = qt_;

        // fence: keep each iteration's loads at their issue point
        __builtin_amdgcn_sched_barrier(0);
    }
}

// ---------------- kernel 3: bf16 MFMA GEMM  C = A @ Bt^T + bias ---------------
// m97 structure: 128x128 tile, BK=64, global_load_lds width-16 staging into
// LINEAR LDS [128][64], 4 waves (2x2), each wave 64x64 via 4x4 frags of
// 16x16x32, 2 barriers per K-step.
#define BM 128
#define BN 128
#define BK 64

__global__ __launch_bounds__(256) void gemm_kernel(
    const unsigned short* __restrict__ A,
    const unsigned short* __restrict__ Bt,
    const float* __restrict__ bias2,
    float* __restrict__ C)
{
    __shared__ __align__(16) unsigned short As[BM * BK];   // 16 KB, linear
    __shared__ __align__(16) unsigned short Bs[BN * BK];   // 16 KB, linear

    const int tid = threadIdx.x;
    const int wave = tid >> 6;
    const int lane = tid & 63;
    const int wr = wave >> 1;          // 0..1 (M dir)
    const int wc = wave & 1;           // 0..1 (N dir)
    const int m0 = blockIdx.x * BM;
    const int n0 = blockIdx.y * BN;
    const int lrow = lane & 15;
    const int lk8 = (lane >> 4) * 8;   // k-offset of this lane's 8 elements

    const int srow = wave * 32;        // first row this wave stages
    const int lrow8 = lane >> 3;       // row within 8-row group
    const int lchunk = lane & 7;       // 16B chunk within row

    f32x4 acc[4][4] = {};

    for (int k0 = 0; k0 < K_CAT; k0 += BK) {
        #pragma unroll
        for (int c = 0; c < 4; ++c) {
            const int row = srow + c * 8 + lrow8;
            {
                const unsigned short* gp = A + (size_t)(m0 + row) * K_CAT + k0 + lchunk * 8;
                unsigned short* lp = As + (srow + c * 8) * BK + lane * 8;
                __builtin_amdgcn_global_load_lds(
                    (const __attribute__((address_space(1))) unsigned int*)gp,
                    (__attribute__((address_space(3))) unsigned int*)lp,
                    16, 0, 0);
            }
            {
                const unsigned short* gp = Bt + (size_t)(n0 + row) * K_CAT + k0 + lchunk * 8;
                unsigned short* lp = Bs + (srow + c * 8) * BK + lane * 8;
                __builtin_amdgcn_global_load_lds(
                    (const __attribute__((address_space(1))) unsigned int*)gp,
                    (__attribute__((address_space(3))) unsigned int*)lp,
                    16, 0, 0);
            }
        }
        __syncthreads();

        bf16x8 af[4][2], bfv[4][2];
        #pragma unroll
        for (int m = 0; m < 4; ++m)
            #pragma unroll
            for (int kk = 0; kk < 2; ++kk)
                af[m][kk] = *reinterpret_cast<const bf16x8*>(
                    &As[(wr * 64 + m * 16 + lrow) * BK + kk * 32 + lk8]);
        #pragma unroll
        for (int n = 0; n < 4; ++n)
            #pragma unroll
            for (int kk = 0; kk < 2; ++kk)
                bfv[n][kk] = *reinterpret_cast<const bf16x8*>(
                    &Bs[(wc * 64 + n * 16 + lrow) * BK + kk * 32 + lk8]);

        #pragma unroll
        for (int kk = 0; kk < 2; ++kk)
            #pragma unroll
            for (int m = 0; m < 4; ++m)
                #pragma unroll
                for (int n = 0; n < 4; ++n)
                    acc[m][n] = __builtin_amdgcn_mfma_f32_16x16x32_bf16(
                        af[m][kk], bfv[n][kk], acc[m][n], 0, 0, 0);
        __syncthreads();
    }

    // -------- epilogue: C/D layout col=lane&15, row=(lane>>4)*4+r  (m89/m91)
    const int rbase = m0 + wr * 64 + (lane >> 4) * 4;
    const int cbase = n0 + wc * 64;
    #pragma unroll
    for (int n = 0; n < 4; ++n) {
        const int col = cbase + n * 16 + lrow;
        const float bv = bias2[col];
        #pragma unroll
        for (int m = 0; m < 4; ++m) {
            const int row0 = rbase + m * 16;
            #pragma unroll
            for (int r = 0; r < 4; ++r) {
                C[(size_t)(row0 + r) * H_DIM + col] = acc[m][n][r] + bv;
            }
        }
    }
}

// ---------------- launcher ----------------
extern "C" void kernel_launch(void* const* d_in, const int* in_sizes, int n_in,
                              void* d_out, int out_size, void* d_ws, size_t ws_size,
                              hipStream_t stream) {
    const float* a      = (const float*)d_in[0];
    const float* v      = (const float*)d_in[1];
    const float* l      = (const float*)d_in[2];
    const float* qmask  = (const float*)d_in[3];
    // d_in[4] umask: unused by reference
    const float* mu_a   = (const float*)d_in[5];
    const float* mu_v   = (const float*)d_in[6];
    const float* mu_l   = (const float*)d_in[7];
    const float* shifta = (const float*)d_in[8];
    const float* shiftv = (const float*)d_in[9];
    const float* turna  = (const float*)d_in[10];
    const float* turnb  = (const float*)d_in[11];
    const float* W1     = (const float*)d_in[12];
    const float* b1     = (const float*)d_in[13];
    const float* W2     = (const float*)d_in[14];
    // d_in[15] b2: cancels in xr+xi
    float* out = (float*)d_out;

    char* ws = (char*)d_ws;
    unsigned short* Afeat = (unsigned short*)ws;                       // M*K_CAT bf16
    size_t offB  = (size_t)M_DIM * K_CAT * sizeof(unsigned short);     // 57.7 MB
    unsigned short* Bt = (unsigned short*)(ws + offB);                 // H*K_CAT bf16
    size_t offBias = offB + (size_t)H_DIM * K_CAT * sizeof(unsigned short);
    float* bias2 = (float*)(ws + offBias);
    size_t offTT = offBias + 4096;
    float4* TT = (float4*)(ws + offTT);                                // T*D float4

    prep_w_kernel<<<(H_DIM * K_CAT + 255) / 256, 256, 0, stream>>>(W1, b1, W2, Bt, bias2);
    prep_tt_kernel<<<(T_DIM * D_DIM + 255) / 256, 256, 0, stream>>>(turna, turnb, TT);
    feat_scan_kernel<<<B_DIM * 2, 256, 0, stream>>>(
        a, v, l, qmask, mu_a, mu_v, mu_l, shifta, shiftv, TT, (unsigned int*)Afeat);
    dim3 grid(M_DIM / BM, H_DIM / BN);
    gemm_kernel<<<grid, 256, 0, stream>>>(Afeat, Bt, bias2, out);
}